// Round 10
// baseline (611.845 us; speedup 1.0000x reference)
//
#include <hip/hip_runtime.h>
#include <hip/hip_fp16.h>

// GCN: 3x (GEMM -> normalized adjacency aggregate) + mean-pool + MLP.
// R2: atomic scatter -> CSR + gather.  R3: hierarchical scan.
// R4: register-tiled GEMM.  R5: MLP probe -> gather LLC-fill-BW bound.
// R6: hs fp16. ->419.  R7: col-partitioned fill. ->409.  R8: fp16 MFMA GEMM. ->345.
// R9: pool split -> only -4us: dispatch gaps ~10us each dominate the residual.
// R10: (a) feature-sliced XCD-affine gather: group=blockIdx&7 handles a 16(8)-feat
//      slice for ALL nodes; slice table 1.6MB fits one XCD L2 -> hs LLC fetch
//      12.8MB total instead of 95MB (8x per-XCD duplication removed).
//      (b) dispatch fusion: memset+pooled-zero into prep_all; scan_part2 folded
//      into scan_part3 (redundant 49-elem scan per block). 16 -> 13 dispatches.
//   out[c] = dinv[c] * ( hs[c] + sum_{(r->c)} hs[r] ),  hs = (X@W) * dinv[row]

#define NGRAPH 100

typedef _Float16 f16x8 __attribute__((ext_vector_type(8)));
typedef float f32x4 __attribute__((ext_vector_type(4)));

// ---------------- prep: Wt transpose-to-fp16 + zero cnt + zero pooled ----------------

__global__ __launch_bounds__(256) void prep_all(const float* __restrict__ W1,
                                                const float* __restrict__ W2,
                                                const float* __restrict__ W3,
                                                __half* __restrict__ Wt1,
                                                __half* __restrict__ Wt2,
                                                __half* __restrict__ Wt3,
                                                int* __restrict__ cnt,
                                                float* __restrict__ pooled, int n) {
    const int idx = blockIdx.x * 256 + threadIdx.x;    // grid 256 blocks = 65536 thr
    if (idx < 16384) {
        int nn = idx >> 7, k = idx & 127;
        Wt1[idx] = __float2half(W1[k * 128 + nn]);
    } else if (idx < 32768) {
        int j = idx - 16384;
        int nn = j >> 7, k = j & 127;
        Wt2[j] = __float2half(W2[k * 128 + nn]);
    } else if (idx < 40960) {
        int j = idx - 32768;
        int nn = j >> 7, k = j & 127;
        Wt3[j] = __float2half(W3[k * 64 + nn]);
    }
    if (idx < n) cnt[idx] = 0;                          // 65536 >= n
    if (idx < NGRAPH * 64) pooled[idx] = 0.0f;
}

// ---------------- degree histogram (int), col-partitioned ----------------

__global__ void deg_kernel(const int* __restrict__ col, int* __restrict__ cnt,
                           int E, int colsPerGroup) {
    const int g  = blockIdx.x & 7;
    const int gb = blockIdx.x >> 3;
    const int nb = gridDim.x >> 3;
    const int lo = g * colsPerGroup, hi = lo + colsPerGroup;
    for (int e = gb * 256 + threadIdx.x; e < E; e += nb * 256) {
        int c = col[e];
        if (c >= lo && c < hi) atomicAdd(&cnt[c], 1);
    }
}

// ---------------- scan pass 1: per-1024-chunk block sums (raw, unscanned) ----------

__global__ __launch_bounds__(256) void scan_part1(const int* __restrict__ cnt,
                                                  int* __restrict__ bsum, int n) {
    __shared__ int ts[256];
    const int b = blockIdx.x, t = threadIdx.x;
    const int base = b * 1024 + t * 4;
    int s = 0;
    if (base + 3 < n) { int4 q = *(const int4*)&cnt[base]; s = q.x + q.y + q.z + q.w; }
    else { for (int i = 0; i < 4; ++i) if (base + i < n) s += cnt[base + i]; }
    ts[t] = s;
    __syncthreads();
    for (int off = 128; off > 0; off >>= 1) {
        if (t < off) ts[t] += ts[t + off];
        __syncthreads();
    }
    if (t == 0) bsum[b] = ts[0];
}

// ---------------- scan pass 2 (folded part2): chunk re-scan + redundant bsum scan ----
// Each block scans raw bsum[0..b) itself (<=48 adds) -> no separate part2 dispatch.
// Also emits cursor (= ptr) and dinv.

__global__ __launch_bounds__(256) void scan_part3(const int* __restrict__ cnt,
                                                  const int* __restrict__ bsum,
                                                  int* __restrict__ ptr,
                                                  int* __restrict__ cursor,
                                                  float* __restrict__ dinv,
                                                  int n, int E) {
    __shared__ int ts[256];
    __shared__ int spre;
    const int b = blockIdx.x, t = threadIdx.x;
    if (t == 0) {
        int p = 0;
        for (int i = 0; i < b; ++i) p += bsum[i];
        spre = p;
    }
    const int base = b * 1024 + t * 4;
    int v0 = 0, v1 = 0, v2 = 0, v3 = 0;
    if (base + 3 < n) {
        int4 q = *(const int4*)&cnt[base]; v0 = q.x; v1 = q.y; v2 = q.z; v3 = q.w;
    } else {
        if (base     < n) v0 = cnt[base];
        if (base + 1 < n) v1 = cnt[base + 1];
        if (base + 2 < n) v2 = cnt[base + 2];
        if (base + 3 < n) v3 = cnt[base + 3];
    }
    const int s = v0 + v1 + v2 + v3;
    ts[t] = s;
    __syncthreads();
    for (int off = 1; off < 256; off <<= 1) {
        int x = (t >= off) ? ts[t - off] : 0;
        __syncthreads();
        ts[t] += x;
        __syncthreads();
    }
    int e0 = ts[t] - s + spre;
    int e1 = e0 + v0, e2 = e1 + v1, e3 = e2 + v2;
    if (base < n) {
        ptr[base] = e0; cursor[base] = e0;
        dinv[base] = 1.0f / sqrtf((float)(v0 + 1));
    }
    if (base + 1 < n) {
        ptr[base + 1] = e1; cursor[base + 1] = e1;
        dinv[base + 1] = 1.0f / sqrtf((float)(v1 + 1));
    }
    if (base + 2 < n) {
        ptr[base + 2] = e2; cursor[base + 2] = e2;
        dinv[base + 2] = 1.0f / sqrtf((float)(v2 + 1));
    }
    if (base + 3 < n) {
        ptr[base + 3] = e3; cursor[base + 3] = e3;
        dinv[base + 3] = 1.0f / sqrtf((float)(v3 + 1));
    }
    if (b == (int)gridDim.x - 1 && t == 255) ptr[n] = E;
}

// ---------------- CSR fill, col-partitioned ----------------

__global__ void fill_kernel(const int* __restrict__ row, const int* __restrict__ col,
                            int* __restrict__ cursor, int* __restrict__ csr,
                            int E, int colsPerGroup) {
    const int g  = blockIdx.x & 7;
    const int gb = blockIdx.x >> 3;
    const int nb = gridDim.x >> 3;
    const int lo = g * colsPerGroup, hi = lo + colsPerGroup;
    for (int e = gb * 256 + threadIdx.x; e < E; e += nb * 256) {
        int c = col[e];
        if (c >= lo && c < hi) {
            int pos = atomicAdd(&cursor[c], 1);
            csr[pos] = row[e];
        }
    }
}

// ---------------- MFMA GEMM: Yh[n,OUT](fp16) = relu?(X + b) @ W * dinv[row] ----------

template <int OUT>
__global__ __launch_bounds__(256) void gemm_mfma(const float* __restrict__ X,
                                                 const __half* __restrict__ Wt,
                                                 const float* __restrict__ bias_in,
                                                 const float* __restrict__ dinv,
                                                 __half* __restrict__ Yh, int n) {
    __shared__ _Float16 Xs[64 * 128];
    __shared__ _Float16 Ws[OUT * 128];
    __shared__ float bs[128];

    const int t = threadIdx.x;
    if (t < 128) bs[t] = (bias_in != nullptr) ? bias_in[t] : 0.0f;
    __syncthreads();

    const int row0 = blockIdx.x * 64;
    const bool do_relu = (bias_in != nullptr);

    for (int c = t; c < 64 * 16; c += 256) {
        const int r = c >> 4, q = c & 15;
        const int gr = row0 + r;
        float4 va = make_float4(0.f, 0.f, 0.f, 0.f), vb = va;
        if (gr < n) {
            va = *(const float4*)&X[(size_t)gr * 128 + q * 8];
            vb = *(const float4*)&X[(size_t)gr * 128 + q * 8 + 4];
        }
        if (do_relu) {
            const int k = q * 8;
            va.x = fmaxf(va.x + bs[k + 0], 0.f);
            va.y = fmaxf(va.y + bs[k + 1], 0.f);
            va.z = fmaxf(va.z + bs[k + 2], 0.f);
            va.w = fmaxf(va.w + bs[k + 3], 0.f);
            vb.x = fmaxf(vb.x + bs[k + 4], 0.f);
            vb.y = fmaxf(vb.y + bs[k + 5], 0.f);
            vb.z = fmaxf(vb.z + bs[k + 6], 0.f);
            vb.w = fmaxf(vb.w + bs[k + 7], 0.f);
        }
        f16x8 hv;
        hv[0] = (_Float16)va.x; hv[1] = (_Float16)va.y;
        hv[2] = (_Float16)va.z; hv[3] = (_Float16)va.w;
        hv[4] = (_Float16)vb.x; hv[5] = (_Float16)vb.y;
        hv[6] = (_Float16)vb.z; hv[7] = (_Float16)vb.w;
        *(f16x8*)&Xs[(size_t)((r << 4) + (q ^ (r & 15))) * 8] = hv;
    }
    for (int c = t; c < OUT * 16; c += 256) {
        const int nn = c >> 4, q = c & 15;
        f16x8 w = *(const f16x8*)&Wt[nn * 128 + q * 8];
        *(f16x8*)&Ws[(size_t)((nn << 4) + (q ^ (nn & 15))) * 8] = w;
    }
    __syncthreads();

    constexpr int NT = OUT / 16;
    const int lane = t & 63, wave = t >> 6;
    const int m = lane & 15, quad = lane >> 4;

    f32x4 acc[NT];
    #pragma unroll
    for (int i = 0; i < NT; ++i) acc[i] = (f32x4){0.f, 0.f, 0.f, 0.f};

    #pragma unroll
    for (int s = 0; s < 4; ++s) {
        const int qa = s * 4 + quad;
        f16x8 a = *(const f16x8*)&Xs[(size_t)(((wave * 16 + m) << 4) + (qa ^ m)) * 8];
        #pragma unroll
        for (int tt = 0; tt < NT; ++tt) {
            f16x8 b = *(const f16x8*)&Ws[(size_t)(((tt * 16 + m) << 4) + (qa ^ m)) * 8];
            acc[tt] = __builtin_amdgcn_mfma_f32_16x16x32_f16(a, b, acc[tt], 0, 0, 0);
        }
    }

    #pragma unroll
    for (int i = 0; i < 4; ++i) {
        const int gr = row0 + wave * 16 + quad * 4 + i;
        if (gr < n) {
            const float dw = dinv[gr];
            #pragma unroll
            for (int tt = 0; tt < NT; ++tt)
                Yh[(size_t)gr * OUT + tt * 16 + m] = __float2half(acc[tt][i] * dw);
        }
    }
}

// ---------------- feature-sliced gather ----------------
// group g = blockIdx&7 (XCD-affine under %8 round-robin) handles features
// [g*SL, (g+1)*SL) for ALL nodes. Slice table (1.6MB/0.8MB) is L2-resident per
// XCD -> hs LLC fetch is compulsory-only. Wave = one destination node:
// EPW edge streams x LPE lanes x dword(2 fp16). xor-shuffle combine.

template <int F>
__global__ __launch_bounds__(256) void gather_sliced(const __half* __restrict__ hs,
                                                     const float* __restrict__ dinv,
                                                     const int* __restrict__ ptr,
                                                     const int* __restrict__ csr,
                                                     float* __restrict__ out, int n) {
    constexpr int SL  = F / 8;       // features per slice: 16 (F=128) or 8 (F=64)
    constexpr int LPE = SL / 2;      // lanes per edge (dwords per slice): 8 or 4
    constexpr int EPW = 64 / LPE;    // edge streams per wave: 8 or 16

    const int g    = blockIdx.x & 7;
    const int cb   = blockIdx.x >> 3;
    const int wave = threadIdx.x >> 6;
    const int lane = threadIdx.x & 63;
    const int c    = cb * 4 + wave;
    if (c >= n) return;

    const int f  = lane % LPE;       // dword index within slice
    const int es = lane / LPE;       // edge stream id
    const int beg = ptr[c], end = ptr[c + 1];
    const float w = dinv[c];
    const size_t coloff = (size_t)g * SL + f * 2;   // half offset within row

    float2 acc = make_float2(0.f, 0.f);
    if (es == 0) {                   // self-loop, added once
        unsigned raw = *(const unsigned*)&hs[(size_t)c * F + coloff];
        float2 v = __half22float2(*(__half2*)&raw);
        acc = v;
    }
    for (int j = beg + es; j < end; j += EPW) {
        int s = csr[j];
        unsigned raw = *(const unsigned*)&hs[(size_t)s * F + coloff];
        float2 v = __half22float2(*(__half2*)&raw);
        acc.x += v.x; acc.y += v.y;
    }
    // combine edge streams: lanes with equal f are strided by LPE
    #pragma unroll
    for (int off = LPE; off < 64; off <<= 1) {
        acc.x += __shfl(acc.x, lane ^ off);
        acc.y += __shfl(acc.y, lane ^ off);
    }
    if (es == 0) {
        float2 o = make_float2(w * acc.x, w * acc.y);
        *(float2*)&out[(size_t)c * F + coloff] = o;
    }
}

// ---------------- pool phase A: pooled[g][f] += relu(h[i][f]+b3[f]) ----------------

__global__ __launch_bounds__(256) void pool_sum(const float* __restrict__ h,
                                                const float* __restrict__ b3,
                                                const int* __restrict__ batch,
                                                float* __restrict__ pooled, int n) {
    const int lane  = threadIdx.x & 63;
    const int wave  = (blockIdx.x * blockDim.x + threadIdx.x) >> 6;
    const int nwav  = (gridDim.x * blockDim.x) >> 6;
    const int chunk = (n + nwav - 1) / nwav;
    const int beg = wave * chunk;
    const int end = min(beg + chunk, n);
    if (beg >= end) return;
    const float bias = b3[lane];
    int curg = batch[beg];
    float acc = 0.f;
    for (int i = beg; i < end; ++i) {
        int g = batch[i];                      // wave-uniform
        if (g != curg) {
            atomicAdd(&pooled[curg * 64 + lane], acc);
            acc = 0.f; curg = g;
        }
        acc += fmaxf(h[(size_t)i * 64 + lane] + bias, 0.f);
    }
    atomicAdd(&pooled[curg * 64 + lane], acc);
}

// ---------------- pool phase B: mean + 64->32->10 MLP ----------------

__global__ __launch_bounds__(64) void mlp_kernel(const float* __restrict__ pooled,
                                                 const int* __restrict__ batch,
                                                 const float* __restrict__ Wf1,
                                                 const float* __restrict__ bf1,
                                                 const float* __restrict__ Wf2,
                                                 const float* __restrict__ bf2,
                                                 float* __restrict__ out, int n) {
    const int g = blockIdx.x;
    const int t = threadIdx.x;

    auto lb = [&](int v) {
        int lo = 0, hi = n;
        while (lo < hi) { int mid = (lo + hi) >> 1; if (batch[mid] < v) lo = mid + 1; else hi = mid; }
        return lo;
    };
    const int cnt = lb(g + 1) - lb(g);

    __shared__ float pm[64];
    __shared__ float hid[32];

    pm[t] = pooled[g * 64 + t] / (float)(cnt > 0 ? cnt : 1);
    __syncthreads();

    if (t < 32) {
        float a = bf1[t];
        #pragma unroll
        for (int k = 0; k < 64; ++k) a += pm[k] * Wf1[k * 32 + t];
        hid[t] = fmaxf(a, 0.f);
    }
    __syncthreads();

    if (t < 10) {
        float a = bf2[t];
        #pragma unroll
        for (int k = 0; k < 32; ++k) a += hid[k] * Wf2[k * 10 + t];
        out[g * 10 + t] = a;
    }
}

// ---------------- launcher ----------------

extern "C" void kernel_launch(void* const* d_in, const int* in_sizes, int n_in,
                              void* d_out, int out_size, void* d_ws, size_t ws_size,
                              hipStream_t stream) {
    const float* x     = (const float*)d_in[0];
    const int*   edge  = (const int*)  d_in[1];
    const int*   batch = (const int*)  d_in[2];
    const float* W1    = (const float*)d_in[3];
    const float* b1    = (const float*)d_in[4];
    const float* W2    = (const float*)d_in[5];
    const float* b2    = (const float*)d_in[6];
    const float* W3    = (const float*)d_in[7];
    const float* b3    = (const float*)d_in[8];
    const float* Wf1   = (const float*)d_in[9];
    const float* bf1   = (const float*)d_in[10];
    const float* Wf2   = (const float*)d_in[11];
    const float* bf2   = (const float*)d_in[12];
    float* out = (float*)d_out;

    const int E = in_sizes[1] / 2;     // 800000
    const int n = in_sizes[2];         // 50000
    const int* row = edge;
    const int* col = edge + E;

    const int nblk = (n + 1023) / 1024;                    // scan chunks (49)
    const int colsPerGroup = (n + 7) / 8;                  // 6250

    const size_t n_pad = ((size_t)n + 64) & ~(size_t)63;   // >= n+1, 64-aligned
    char* wsb = (char*)d_ws;
    int*    cnt    = (int*)wsb;                  wsb += n_pad * 4;   // reused as cursor
    int*    ptr    = (int*)wsb;                  wsb += n_pad * 4;
    float*  dinv   = (float*)wsb;                wsb += n_pad * 4;
    int*    bsum   = (int*)wsb;                  wsb += 256 * 4;
    float*  pooled = (float*)wsb;                wsb += NGRAPH * 64 * 4;
    int*    csr    = (int*)wsb;                  wsb += (((size_t)E + 63) & ~(size_t)63) * 4;
    __half* Wt1    = (__half*)wsb;               wsb += 16384 * 2;
    __half* Wt2    = (__half*)wsb;               wsb += 16384 * 2;
    __half* Wt3    = (__half*)wsb;               wsb += 8192 * 2;
    __half* bufA   = (__half*)wsb;               wsb += (size_t)n * 128 * 2;   // fp16 hs
    float*  bufB   = (float*)wsb;

    // ---- prep + CSR build (once, reused for all 3 layers) ----
    prep_all<<<256, 256, 0, stream>>>(W1, W2, W3, Wt1, Wt2, Wt3, cnt, pooled, n);
    deg_kernel<<<1024, 256, 0, stream>>>(col, cnt, E, colsPerGroup);
    scan_part1<<<nblk, 256, 0, stream>>>(cnt, bsum, n);
    scan_part3<<<nblk, 256, 0, stream>>>(cnt, bsum, ptr, cnt, dinv, n, E);  // cursor aliases cnt
    fill_kernel<<<1024, 256, 0, stream>>>(row, col, cnt, csr, E, colsPerGroup);

    const int ggemm = (n + 63) / 64;                       // 64 rows per block
    const int gslice = ((n + 3) / 4) * 8;                  // 4 nodes/block x 8 groups

    // layer 1
    gemm_mfma<128><<<ggemm, 256, 0, stream>>>(x, Wt1, nullptr, dinv, bufA, n);
    gather_sliced<128><<<gslice, 256, 0, stream>>>(bufA, dinv, ptr, csr, bufB, n);
    // layer 2
    gemm_mfma<128><<<ggemm, 256, 0, stream>>>(bufB, Wt2, b1, dinv, bufA, n);
    gather_sliced<128><<<gslice, 256, 0, stream>>>(bufA, dinv, ptr, csr, bufB, n);
    // layer 3 (64-wide)
    gemm_mfma<64><<<ggemm, 256, 0, stream>>>(bufB, Wt3, b2, dinv, bufA, n);
    gather_sliced<64><<<gslice, 256, 0, stream>>>(bufA, dinv, ptr, csr, bufB, n);

    // head: relu(+b3) -> mean pool (2-phase) -> MLP
    pool_sum<<<200, 256, 0, stream>>>(bufB, b3, batch, pooled, n);
    mlp_kernel<<<NGRAPH, 64, 0, stream>>>(pooled, batch, Wf1, bf1, Wf2, bf2, out, n);
}

// Round 11
// 337.852 us; speedup vs baseline: 1.8110x; 1.8110x over previous
//
#include <hip/hip_runtime.h>
#include <hip/hip_fp16.h>

// GCN: 3x (GEMM -> normalized adjacency aggregate) + mean-pool + MLP.
// R2: scatter->CSR+gather. R3: hier scan. R4: reg-tiled GEMM. R6: hs fp16 (419).
// R7: col-partitioned fill (409). R8: fp16 MFMA GEMM (345). R9: pool split (341).
// R10: feature-sliced gather -> REGRESSION (traffic is line-granular; intra-row
//      slicing cannot cut per-XCD LLC duplication). Reverted.
// R11: R9 gather restored + gather OUTPUT fp16 (bufB): halves gather write,
//      GEMM stage read (fp16-input MFMA path), pool read. Keep R10's dispatch
//      fusions (prep_all zeroes cnt+pooled; scan_part2 folded into part3).
//   out[c] = dinv[c] * ( hs[c] + sum_{(r->c)} hs[r] ),  hs = (X@W) * dinv[row]

#define NGRAPH 100

typedef _Float16 f16x8 __attribute__((ext_vector_type(8)));
typedef float f32x4 __attribute__((ext_vector_type(4)));

// ---------------- prep: Wt transpose-to-fp16 + zero cnt + zero pooled ----------------

__global__ __launch_bounds__(256) void prep_all(const float* __restrict__ W1,
                                                const float* __restrict__ W2,
                                                const float* __restrict__ W3,
                                                __half* __restrict__ Wt1,
                                                __half* __restrict__ Wt2,
                                                __half* __restrict__ Wt3,
                                                int* __restrict__ cnt,
                                                float* __restrict__ pooled, int n) {
    const int idx = blockIdx.x * 256 + threadIdx.x;    // 256 blocks = 65536 thr
    if (idx < 16384) {
        int nn = idx >> 7, k = idx & 127;
        Wt1[idx] = __float2half(W1[k * 128 + nn]);
    } else if (idx < 32768) {
        int j = idx - 16384;
        int nn = j >> 7, k = j & 127;
        Wt2[j] = __float2half(W2[k * 128 + nn]);
    } else if (idx < 40960) {
        int j = idx - 32768;
        int nn = j >> 7, k = j & 127;
        Wt3[j] = __float2half(W3[k * 64 + nn]);
    }
    if (idx < n) cnt[idx] = 0;                          // 65536 >= n
    if (idx < NGRAPH * 64) pooled[idx] = 0.0f;
}

// ---------------- degree histogram (int), col-partitioned ----------------

__global__ void deg_kernel(const int* __restrict__ col, int* __restrict__ cnt,
                           int E, int colsPerGroup) {
    const int g  = blockIdx.x & 7;
    const int gb = blockIdx.x >> 3;
    const int nb = gridDim.x >> 3;
    const int lo = g * colsPerGroup, hi = lo + colsPerGroup;
    for (int e = gb * 256 + threadIdx.x; e < E; e += nb * 256) {
        int c = col[e];
        if (c >= lo && c < hi) atomicAdd(&cnt[c], 1);
    }
}

// ---------------- scan pass 1: per-1024-chunk block sums ----------------

__global__ __launch_bounds__(256) void scan_part1(const int* __restrict__ cnt,
                                                  int* __restrict__ bsum, int n) {
    __shared__ int ts[256];
    const int b = blockIdx.x, t = threadIdx.x;
    const int base = b * 1024 + t * 4;
    int s = 0;
    if (base + 3 < n) { int4 q = *(const int4*)&cnt[base]; s = q.x + q.y + q.z + q.w; }
    else { for (int i = 0; i < 4; ++i) if (base + i < n) s += cnt[base + i]; }
    ts[t] = s;
    __syncthreads();
    for (int off = 128; off > 0; off >>= 1) {
        if (t < off) ts[t] += ts[t + off];
        __syncthreads();
    }
    if (t == 0) bsum[b] = ts[0];
}

// ---------------- scan pass 2: chunk re-scan + per-block redundant bsum scan ----------

__global__ __launch_bounds__(256) void scan_part3(const int* __restrict__ cnt,
                                                  const int* __restrict__ bsum,
                                                  int* __restrict__ ptr,
                                                  int* __restrict__ cursor,
                                                  float* __restrict__ dinv,
                                                  int n, int E) {
    __shared__ int ts[256];
    __shared__ int spre;
    const int b = blockIdx.x, t = threadIdx.x;
    if (t == 0) {
        int p = 0;
        for (int i = 0; i < b; ++i) p += bsum[i];
        spre = p;
    }
    const int base = b * 1024 + t * 4;
    int v0 = 0, v1 = 0, v2 = 0, v3 = 0;
    if (base + 3 < n) {
        int4 q = *(const int4*)&cnt[base]; v0 = q.x; v1 = q.y; v2 = q.z; v3 = q.w;
    } else {
        if (base     < n) v0 = cnt[base];
        if (base + 1 < n) v1 = cnt[base + 1];
        if (base + 2 < n) v2 = cnt[base + 2];
        if (base + 3 < n) v3 = cnt[base + 3];
    }
    const int s = v0 + v1 + v2 + v3;
    ts[t] = s;
    __syncthreads();
    for (int off = 1; off < 256; off <<= 1) {
        int x = (t >= off) ? ts[t - off] : 0;
        __syncthreads();
        ts[t] += x;
        __syncthreads();
    }
    int e0 = ts[t] - s + spre;
    int e1 = e0 + v0, e2 = e1 + v1, e3 = e2 + v2;
    if (base < n) {
        ptr[base] = e0; cursor[base] = e0;
        dinv[base] = 1.0f / sqrtf((float)(v0 + 1));
    }
    if (base + 1 < n) {
        ptr[base + 1] = e1; cursor[base + 1] = e1;
        dinv[base + 1] = 1.0f / sqrtf((float)(v1 + 1));
    }
    if (base + 2 < n) {
        ptr[base + 2] = e2; cursor[base + 2] = e2;
        dinv[base + 2] = 1.0f / sqrtf((float)(v2 + 1));
    }
    if (base + 3 < n) {
        ptr[base + 3] = e3; cursor[base + 3] = e3;
        dinv[base + 3] = 1.0f / sqrtf((float)(v3 + 1));
    }
    if (b == (int)gridDim.x - 1 && t == 255) ptr[n] = E;
}

// ---------------- CSR fill, col-partitioned ----------------

__global__ void fill_kernel(const int* __restrict__ row, const int* __restrict__ col,
                            int* __restrict__ cursor, int* __restrict__ csr,
                            int E, int colsPerGroup) {
    const int g  = blockIdx.x & 7;
    const int gb = blockIdx.x >> 3;
    const int nb = gridDim.x >> 3;
    const int lo = g * colsPerGroup, hi = lo + colsPerGroup;
    for (int e = gb * 256 + threadIdx.x; e < E; e += nb * 256) {
        int c = col[e];
        if (c >= lo && c < hi) {
            int pos = atomicAdd(&cursor[c], 1);
            csr[pos] = row[e];
        }
    }
}

// ---------------- MFMA GEMM: Yh(fp16) = relu?(X + b) @ W * dinv[row] ----------
// F16IN: X is fp16 (gather output); else fp32 (layer-1 node features).

template <int OUT, bool F16IN>
__global__ __launch_bounds__(256) void gemm_mfma(const void* __restrict__ Xv,
                                                 const __half* __restrict__ Wt,
                                                 const float* __restrict__ bias_in,
                                                 const float* __restrict__ dinv,
                                                 __half* __restrict__ Yh, int n) {
    __shared__ _Float16 Xs[64 * 128];
    __shared__ _Float16 Ws[OUT * 128];
    __shared__ float bs[128];

    const float*  Xf = (const float*)Xv;
    const __half* Xh = (const __half*)Xv;

    const int t = threadIdx.x;
    if (t < 128) bs[t] = (bias_in != nullptr) ? bias_in[t] : 0.0f;
    __syncthreads();

    const int row0 = blockIdx.x * 64;
    const bool do_relu = (bias_in != nullptr);

    for (int c = t; c < 64 * 16; c += 256) {
        const int r = c >> 4, q = c & 15;
        const int gr = row0 + r;
        float vals[8];
        #pragma unroll
        for (int i = 0; i < 8; ++i) vals[i] = 0.0f;
        if (gr < n) {
            if (F16IN) {
                f16x8 hv = *(const f16x8*)&Xh[(size_t)gr * 128 + q * 8];
                #pragma unroll
                for (int i = 0; i < 8; ++i) vals[i] = (float)hv[i];
            } else {
                float4 va = *(const float4*)&Xf[(size_t)gr * 128 + q * 8];
                float4 vb = *(const float4*)&Xf[(size_t)gr * 128 + q * 8 + 4];
                vals[0] = va.x; vals[1] = va.y; vals[2] = va.z; vals[3] = va.w;
                vals[4] = vb.x; vals[5] = vb.y; vals[6] = vb.z; vals[7] = vb.w;
            }
        }
        if (do_relu) {
            const int k = q * 8;
            #pragma unroll
            for (int i = 0; i < 8; ++i) vals[i] = fmaxf(vals[i] + bs[k + i], 0.f);
        }
        f16x8 hv;
        #pragma unroll
        for (int i = 0; i < 8; ++i) hv[i] = (_Float16)vals[i];
        *(f16x8*)&Xs[(size_t)((r << 4) + (q ^ (r & 15))) * 8] = hv;
    }
    for (int c = t; c < OUT * 16; c += 256) {
        const int nn = c >> 4, q = c & 15;
        f16x8 w = *(const f16x8*)&Wt[nn * 128 + q * 8];
        *(f16x8*)&Ws[(size_t)((nn << 4) + (q ^ (nn & 15))) * 8] = w;
    }
    __syncthreads();

    constexpr int NT = OUT / 16;
    const int lane = t & 63, wave = t >> 6;
    const int m = lane & 15, quad = lane >> 4;

    f32x4 acc[NT];
    #pragma unroll
    for (int i = 0; i < NT; ++i) acc[i] = (f32x4){0.f, 0.f, 0.f, 0.f};

    #pragma unroll
    for (int s = 0; s < 4; ++s) {
        const int qa = s * 4 + quad;
        f16x8 a = *(const f16x8*)&Xs[(size_t)(((wave * 16 + m) << 4) + (qa ^ m)) * 8];
        #pragma unroll
        for (int tt = 0; tt < NT; ++tt) {
            f16x8 b = *(const f16x8*)&Ws[(size_t)(((tt * 16 + m) << 4) + (qa ^ m)) * 8];
            acc[tt] = __builtin_amdgcn_mfma_f32_16x16x32_f16(a, b, acc[tt], 0, 0, 0);
        }
    }

    #pragma unroll
    for (int i = 0; i < 4; ++i) {
        const int gr = row0 + wave * 16 + quad * 4 + i;
        if (gr < n) {
            const float dw = dinv[gr];
            #pragma unroll
            for (int tt = 0; tt < NT; ++tt)
                Yh[(size_t)gr * OUT + tt * 16 + m] = __float2half(acc[tt][i] * dw);
        }
    }
}

// ---------------- gather (R9 structure): fp16 in, fp32 accum, fp16 out ----------------
// outh[c,:] = fp16( dinv[c] * (hs[c,:] + sum_in hs[src,:]) )
// F=128: 2 half-wave edge streams, 32 lanes x 8B(4 halfs)/row; F=64: 4 streams x 16 lanes.

template <int F>
__global__ void gather_kernel(const __half* __restrict__ hs, const float* __restrict__ dinv,
                              const int* __restrict__ ptr, const int* __restrict__ csr,
                              __half* __restrict__ outh, int n) {
    const int lane = threadIdx.x & 63;
    const int c = (blockIdx.x * blockDim.x + threadIdx.x) >> 6;
    if (c >= n) return;
    const int beg = ptr[c], end = ptr[c + 1];
    const float w = dinv[c];
    const float2* hq = (const float2*)hs;

    auto cvt = [](float2 raw) {
        __half2 ha = *(__half2*)&raw.x;
        __half2 hb = *(__half2*)&raw.y;
        float2 fa = __half22float2(ha);
        float2 fb = __half22float2(hb);
        return make_float4(fa.x, fa.y, fb.x, fb.y);
    };
    auto pack = [](float4 v) {
        float2 o;
        *(__half2*)&o.x = __float22half2_rn(make_float2(v.x, v.y));
        *(__half2*)&o.y = __float22half2_rn(make_float2(v.z, v.w));
        return o;
    };

    if (F == 128) {
        const int half = lane >> 5;
        const int l    = lane & 31;
        float4 acc = make_float4(0.f, 0.f, 0.f, 0.f);
        if (half == 0) acc = cvt(hq[(size_t)c * 32 + l]);
        int j = beg + half;
        for (; j + 6 < end; j += 8) {
            int s0 = csr[j], s1 = csr[j + 2], s2 = csr[j + 4], s3 = csr[j + 6];
            float4 v0 = cvt(hq[(size_t)s0 * 32 + l]);
            float4 v1 = cvt(hq[(size_t)s1 * 32 + l]);
            float4 v2 = cvt(hq[(size_t)s2 * 32 + l]);
            float4 v3 = cvt(hq[(size_t)s3 * 32 + l]);
            acc.x += v0.x + v1.x + v2.x + v3.x;
            acc.y += v0.y + v1.y + v2.y + v3.y;
            acc.z += v0.z + v1.z + v2.z + v3.z;
            acc.w += v0.w + v1.w + v2.w + v3.w;
        }
        for (; j < end; j += 2) {
            float4 v = cvt(hq[(size_t)csr[j] * 32 + l]);
            acc.x += v.x; acc.y += v.y; acc.z += v.z; acc.w += v.w;
        }
        acc.x += __shfl(acc.x, lane ^ 32);
        acc.y += __shfl(acc.y, lane ^ 32);
        acc.z += __shfl(acc.z, lane ^ 32);
        acc.w += __shfl(acc.w, lane ^ 32);
        if (half == 0) {
            float4 o = make_float4(w * acc.x, w * acc.y, w * acc.z, w * acc.w);
            *(float2*)&outh[(size_t)c * 128 + l * 4] = pack(o);
        }
    } else {     // F == 64
        const int q = lane >> 4;
        const int l = lane & 15;
        float4 acc = make_float4(0.f, 0.f, 0.f, 0.f);
        if (q == 0) acc = cvt(hq[(size_t)c * 16 + l]);
        int j = beg + q;
        for (; j + 12 < end; j += 16) {
            int s0 = csr[j], s1 = csr[j + 4], s2 = csr[j + 8], s3 = csr[j + 12];
            float4 v0 = cvt(hq[(size_t)s0 * 16 + l]);
            float4 v1 = cvt(hq[(size_t)s1 * 16 + l]);
            float4 v2 = cvt(hq[(size_t)s2 * 16 + l]);
            float4 v3 = cvt(hq[(size_t)s3 * 16 + l]);
            acc.x += v0.x + v1.x + v2.x + v3.x;
            acc.y += v0.y + v1.y + v2.y + v3.y;
            acc.z += v0.z + v1.z + v2.z + v3.z;
            acc.w += v0.w + v1.w + v2.w + v3.w;
        }
        for (; j < end; j += 4) {
            float4 v = cvt(hq[(size_t)csr[j] * 16 + l]);
            acc.x += v.x; acc.y += v.y; acc.z += v.z; acc.w += v.w;
        }
        acc.x += __shfl(acc.x, lane ^ 16);
        acc.y += __shfl(acc.y, lane ^ 16);
        acc.z += __shfl(acc.z, lane ^ 16);
        acc.w += __shfl(acc.w, lane ^ 16);
        acc.x += __shfl(acc.x, lane ^ 32);
        acc.y += __shfl(acc.y, lane ^ 32);
        acc.z += __shfl(acc.z, lane ^ 32);
        acc.w += __shfl(acc.w, lane ^ 32);
        if (q == 0) {
            float4 o = make_float4(w * acc.x, w * acc.y, w * acc.z, w * acc.w);
            *(float2*)&outh[(size_t)c * 64 + l * 4] = pack(o);
        }
    }
}

// ---------------- pool phase A: pooled[g][f] += relu(h[i][f]+b3[f]), h fp16 ----------

__global__ __launch_bounds__(256) void pool_sum(const __half* __restrict__ h,
                                                const float* __restrict__ b3,
                                                const int* __restrict__ batch,
                                                float* __restrict__ pooled, int n) {
    const int lane  = threadIdx.x & 63;
    const int wave  = (blockIdx.x * blockDim.x + threadIdx.x) >> 6;
    const int nwav  = (gridDim.x * blockDim.x) >> 6;
    const int chunk = (n + nwav - 1) / nwav;
    const int beg = wave * chunk;
    const int end = min(beg + chunk, n);
    if (beg >= end) return;
    const float bias = b3[lane];
    int curg = batch[beg];
    float acc = 0.f;
    for (int i = beg; i < end; ++i) {
        int g = batch[i];                      // wave-uniform
        if (g != curg) {
            atomicAdd(&pooled[curg * 64 + lane], acc);
            acc = 0.f; curg = g;
        }
        acc += fmaxf(__half2float(h[(size_t)i * 64 + lane]) + bias, 0.f);
    }
    atomicAdd(&pooled[curg * 64 + lane], acc);
}

// ---------------- pool phase B: mean + 64->32->10 MLP ----------------

__global__ __launch_bounds__(64) void mlp_kernel(const float* __restrict__ pooled,
                                                 const int* __restrict__ batch,
                                                 const float* __restrict__ Wf1,
                                                 const float* __restrict__ bf1,
                                                 const float* __restrict__ Wf2,
                                                 const float* __restrict__ bf2,
                                                 float* __restrict__ out, int n) {
    const int g = blockIdx.x;
    const int t = threadIdx.x;

    auto lb = [&](int v) {
        int lo = 0, hi = n;
        while (lo < hi) { int mid = (lo + hi) >> 1; if (batch[mid] < v) lo = mid + 1; else hi = mid; }
        return lo;
    };
    const int cnt = lb(g + 1) - lb(g);

    __shared__ float pm[64];
    __shared__ float hid[32];

    pm[t] = pooled[g * 64 + t] / (float)(cnt > 0 ? cnt : 1);
    __syncthreads();

    if (t < 32) {
        float a = bf1[t];
        #pragma unroll
        for (int k = 0; k < 64; ++k) a += pm[k] * Wf1[k * 32 + t];
        hid[t] = fmaxf(a, 0.f);
    }
    __syncthreads();

    if (t < 10) {
        float a = bf2[t];
        #pragma unroll
        for (int k = 0; k < 32; ++k) a += hid[k] * Wf2[k * 10 + t];
        out[g * 10 + t] = a;
    }
}

// ---------------- launcher ----------------

extern "C" void kernel_launch(void* const* d_in, const int* in_sizes, int n_in,
                              void* d_out, int out_size, void* d_ws, size_t ws_size,
                              hipStream_t stream) {
    const float* x     = (const float*)d_in[0];
    const int*   edge  = (const int*)  d_in[1];
    const int*   batch = (const int*)  d_in[2];
    const float* W1    = (const float*)d_in[3];
    const float* b1    = (const float*)d_in[4];
    const float* W2    = (const float*)d_in[5];
    const float* b2    = (const float*)d_in[6];
    const float* W3    = (const float*)d_in[7];
    const float* b3    = (const float*)d_in[8];
    const float* Wf1   = (const float*)d_in[9];
    const float* bf1   = (const float*)d_in[10];
    const float* Wf2   = (const float*)d_in[11];
    const float* bf2   = (const float*)d_in[12];
    float* out = (float*)d_out;

    const int E = in_sizes[1] / 2;     // 800000
    const int n = in_sizes[2];         // 50000
    const int* row = edge;
    const int* col = edge + E;

    const int nblk = (n + 1023) / 1024;                    // scan chunks (49)
    const int colsPerGroup = (n + 7) / 8;                  // 6250

    const size_t n_pad = ((size_t)n + 64) & ~(size_t)63;   // >= n+1, 64-aligned
    char* wsb = (char*)d_ws;
    int*    cnt    = (int*)wsb;                  wsb += n_pad * 4;   // reused as cursor
    int*    ptr    = (int*)wsb;                  wsb += n_pad * 4;
    float*  dinv   = (float*)wsb;                wsb += n_pad * 4;
    int*    bsum   = (int*)wsb;                  wsb += 256 * 4;
    float*  pooled = (float*)wsb;                wsb += NGRAPH * 64 * 4;
    int*    csr    = (int*)wsb;                  wsb += (((size_t)E + 63) & ~(size_t)63) * 4;
    __half* Wt1    = (__half*)wsb;               wsb += 16384 * 2;
    __half* Wt2    = (__half*)wsb;               wsb += 16384 * 2;
    __half* Wt3    = (__half*)wsb;               wsb += 8192 * 2;
    __half* bufA   = (__half*)wsb;               wsb += (size_t)n * 128 * 2;   // fp16 hs
    __half* bufB   = (__half*)wsb;                                            // fp16 gathered

    // ---- prep + CSR build (once, reused for all 3 layers) ----
    prep_all<<<256, 256, 0, stream>>>(W1, W2, W3, Wt1, Wt2, Wt3, cnt, pooled, n);
    deg_kernel<<<1024, 256, 0, stream>>>(col, cnt, E, colsPerGroup);
    scan_part1<<<nblk, 256, 0, stream>>>(cnt, bsum, n);
    scan_part3<<<nblk, 256, 0, stream>>>(cnt, bsum, ptr, cnt, dinv, n, E);  // cursor aliases cnt
    fill_kernel<<<1024, 256, 0, stream>>>(row, col, cnt, csr, E, colsPerGroup);

    const int ggemm = (n + 63) / 64;                       // 64 rows per block
    const int gath_grid = (n * 64 + 255) / 256;            // one wave per node

    // layer 1 (fp32 input)
    gemm_mfma<128, false><<<ggemm, 256, 0, stream>>>(x, Wt1, nullptr, dinv, bufA, n);
    gather_kernel<128><<<gath_grid, 256, 0, stream>>>(bufA, dinv, ptr, csr, bufB, n);
    // layer 2 (fp16 input)
    gemm_mfma<128, true><<<ggemm, 256, 0, stream>>>(bufB, Wt2, b1, dinv, bufA, n);
    gather_kernel<128><<<gath_grid, 256, 0, stream>>>(bufA, dinv, ptr, csr, bufB, n);
    // layer 3 (64-wide, fp16 input)
    gemm_mfma<64, true><<<ggemm, 256, 0, stream>>>(bufB, Wt3, b2, dinv, bufA, n);
    gather_kernel<64><<<gath_grid, 256, 0, stream>>>(bufA, dinv, ptr, csr, bufB, n);

    // head: relu(+b3) -> mean pool (2-phase) -> MLP
    pool_sum<<<200, 256, 0, stream>>>(bufB, b3, batch, pooled, n);
    mlp_kernel<<<NGRAPH, 64, 0, stream>>>(pooled, batch, Wf1, bf1, Wf2, bf2, out, n);
}